// Round 8
// baseline (36.605 us; speedup 1.0000x reference)
//
#include <hip/hip_runtime.h>
#include <hip/hip_bf16.h>
#include <math.h>

// ---------------------------------------------------------------------------
// DPP helpers (controls validated bit-exact rounds 5-7): 0xB1 quad_perm=xor1,
// 0x4E quad_perm=xor2, 0x141 row_half_mirror=xor7, 0x140 row_mirror=xor15,
// 0x142 row_bcast15, 0x143 row_bcast31. Reduce shape: 6 steps -> lane63 ->
// readlane. bound_ctrl zero-fill only pollutes lanes outside lane63's
// dependency cone (0-15 at bcast15, 0-31 at bcast31) — safe for u32 min too.
// ---------------------------------------------------------------------------
template <int CTRL>
__device__ __forceinline__ int dpp_i(int x) {
  return __builtin_amdgcn_update_dpp(0, x, CTRL, 0xF, 0xF, true);
}
template <int CTRL>
__device__ __forceinline__ float dpp_f(float x) {
  return __int_as_float(__builtin_amdgcn_update_dpp(0, __float_as_int(x), CTRL, 0xF, 0xF, true));
}
__device__ __forceinline__ unsigned umin_(unsigned a, unsigned b) { return a < b ? a : b; }
__device__ __forceinline__ int imin_(int a, int b) { return a < b ? a : b; }

// ---------------------------------------------------------------------------
// Per-tensor normalized-softmax gather: c = e_g / sqrt(sum e^2). (S cancels
// exactly — validated rounds 6-7, absmax 0.0.) Reduction trees unchanged.
// ---------------------------------------------------------------------------
template <int NK>
__device__ __forceinline__ float tensor_c(const float* __restrict__ row,
                                          int idx, int lane) {
  float x[4][4];
  float xg = row[idx];
  if (NK == 4) {
    #pragma unroll
    for (int k = 0; k < 4; ++k) {
      float4 v4 = *reinterpret_cast<const float4*>(row + (k << 8) + lane * 4);
      x[k][0] = v4.x; x[k][1] = v4.y; x[k][2] = v4.z; x[k][3] = v4.w;
    }
  } else {
    #pragma unroll
    for (int k = 0; k < 4; ++k) {
      float2 v2 = *reinterpret_cast<const float2*>(row + (k << 7) + lane * 2);
      x[k][0] = v2.x; x[k][1] = v2.y; x[k][2] = 0.0f; x[k][3] = 0.0f;
    }
  }

  float m = -INFINITY;
  #pragma unroll
  for (int k = 0; k < 4; ++k) {
    #pragma unroll
    for (int e = 0; e < 4; ++e) if (e < NK) {
      if (isnan(x[k][e])) x[k][e] = -1e9f;
      m = fmaxf(m, x[k][e]);
    }
  }
  m = fmaxf(m, dpp_f<0xB1>(m));
  m = fmaxf(m, dpp_f<0x4E>(m));
  m = fmaxf(m, dpp_f<0x141>(m));
  m = fmaxf(m, dpp_f<0x140>(m));
  m = fmaxf(m, dpp_f<0x142>(m));
  m = fmaxf(m, dpp_f<0x143>(m));
  float mx = __int_as_float(__builtin_amdgcn_readlane(__float_as_int(m), 63));

  float q[4];
  #pragma unroll
  for (int k = 0; k < 4; ++k) {
    float ls = 0.0f;
    #pragma unroll
    for (int e = 0; e < 4; ++e) if (e < NK) {
      float ev = expf(x[k][e] - mx);
      ls = fmaf(ev, ev, ls);
    }
    q[k] = ls;
  }
  #pragma unroll
  for (int k = 0; k < 4; ++k) {
    q[k] += __shfl_xor(q[k], 32);
    q[k] += __shfl_xor(q[k], 16);
    q[k] += __shfl_xor(q[k], 8);
    q[k] += __shfl_xor(q[k], 4);
    q[k] += dpp_f<0x4E>(q[k]);
    q[k] += dpp_f<0xB1>(q[k]);
  }
  float Q = (q[0] + q[1]) + (q[2] + q[3]);

  if (isnan(xg)) xg = -1e9f;
  float pg = expf(xg - mx);
  return pg / sqrtf(Q);
}

// ---------------------------------------------------------------------------
// Kernel 1 (fused): validated round-7 structure. T now stores the SORTABLE
// transform ~bits(cost) (all costs strictly negative finite -> ~bits is an
// exact order isomorphism; 0xFFFFFFFF is unreachable and serves as EXCLUDED).
// ---------------------------------------------------------------------------
__global__ __launch_bounds__(256, 8) void cost_kernel_fused(
    const float* __restrict__ rel,
    const float* __restrict__ hs, const float* __restrict__ he,
    const float* __restrict__ ts, const float* __restrict__ te,
    const int* __restrict__ grel,
    const int* __restrict__ ghs, const int* __restrict__ ghe,
    const int* __restrict__ gts, const int* __restrict__ gte,
    float* __restrict__ cost, unsigned* __restrict__ T)
{
  __shared__ float smB[2][32];
  const int wid   = threadIdx.x >> 6;
  const int lane  = threadIdx.x & 63;
  const int pair  = wid >> 1;
  const int group = wid & 1;
  const int bq    = (blockIdx.x << 1) | pair;
  const int b     = bq >> 9;
  const int gl    = (b << 5) + (lane & 31);

  float accA = 0.0f;
  if (group == 0) {
    accA =        tensor_c<2>(rel + (size_t)bq * 512,  grel[gl], lane);
    accA = fmaf(0.5f, tensor_c<4>(hs + (size_t)bq * 1024, ghs[gl], lane), accA);
    accA = fmaf(0.5f, tensor_c<4>(he + (size_t)bq * 1024, ghe[gl], lane), accA);
  } else {
    float accB = 0.5f * tensor_c<4>(ts + (size_t)bq * 1024, gts[gl], lane);
    accB = fmaf(0.5f, tensor_c<4>(te + (size_t)bq * 1024, gte[gl], lane), accB);
    if (lane < 32) smB[pair][lane] = accB;
  }
  __syncthreads();
  if (group == 0 && lane < 32) {
    float tot = -(accA + smB[pair][lane]);       // same expr as rounds 6-7
    cost[(size_t)bq * 32 + lane] = tot;
    T[(size_t)b * 16384 + lane * 512 + (bq & 511)] = ~__float_as_uint(tot);
  }
}

// Fallback (ws too small): validated single-wave cost straight to out.
__global__ __launch_bounds__(256, 4) void cost_kernel_single(
    const float* __restrict__ rel,
    const float* __restrict__ hs, const float* __restrict__ he,
    const float* __restrict__ ts, const float* __restrict__ te,
    const int* __restrict__ grel,
    const int* __restrict__ ghs, const int* __restrict__ ghe,
    const int* __restrict__ gts, const int* __restrict__ gte,
    float* __restrict__ cost)
{
  const int wid  = threadIdx.x >> 6;
  const int lane = threadIdx.x & 63;
  const int bq   = (blockIdx.x << 2) | wid;
  const int b    = bq >> 9;
  const int gl   = (b << 5) + (lane & 31);
  float acc;
  acc =        tensor_c<2>(rel + (size_t)bq * 512,  grel[gl], lane);
  acc = fmaf(0.5f, tensor_c<4>(hs + (size_t)bq * 1024, ghs[gl], lane), acc);
  acc = fmaf(0.5f, tensor_c<4>(he + (size_t)bq * 1024, ghe[gl], lane), acc);
  acc = fmaf(0.5f, tensor_c<4>(ts + (size_t)bq * 1024, gts[gl], lane), acc);
  acc = fmaf(0.5f, tensor_c<4>(te + (size_t)bq * 1024, gte[gl], lane), acc);
  if (lane < 32) cost[(size_t)bq * 32 + lane] = -acc;
}

// ---------------------------------------------------------------------------
// Kernel 2: collapsed reference-JV replica (derivation validated r3-r7).
// Round-8: sortable-u32 domain; alive/freem as 8x u64 SCALAR masks (SALU
// cselect chains, off the single-wave VALU pipe); branchless exact locate
// via 8 ballots + s_ff1 (min-j tie-break identical to reference); VGPR am
// mask touched only in the rare (E[~1/batch]) kill branch. 4-wave staging,
// waves 1-3 exit after the barrier; turn loop is barrier-free single-wave.
// ---------------------------------------------------------------------------
template <bool PRETRANS>
__global__ __launch_bounds__(256) void hungarian_kernel(
    const void* __restrict__ srcv, float* __restrict__ out)
{
  __shared__ unsigned ct[32 * 512];   // ct[g*512+j] = sortable ~bits(cost)
  __shared__ int rows_s[32];

  const int b   = blockIdx.x;
  const int tid = threadIdx.x;

  if (PRETRANS) {                      // pure linear copy, already transformed
    const uint4* T4 = reinterpret_cast<const uint4*>(
        (const unsigned*)srcv + (size_t)b * 16384);
    #pragma unroll 4
    for (int it = tid; it < 4096; it += 256)
      *reinterpret_cast<uint4*>(ct + (it << 2)) = T4[it];
  } else {                             // transpose + transform at stage
    const float4* C4 = reinterpret_cast<const float4*>(
        (const float*)srcv + (size_t)b * 16384);
    #pragma unroll 2
    for (int base = tid; base < 4096; base += 256) {
      float4 v = C4[base];
      int e0 = base << 2, j = e0 >> 5, g = e0 & 31;
      ct[(g + 0) * 512 + j] = ~__float_as_uint(v.x);
      ct[(g + 1) * 512 + j] = ~__float_as_uint(v.y);
      ct[(g + 2) * 512 + j] = ~__float_as_uint(v.z);
      ct[(g + 3) * 512 + j] = ~__float_as_uint(v.w);
    }
  }
  __syncthreads();
  if (tid >= 64) return;               // turn loop is single-wave
  const int lane = tid;

  unsigned long long s_alive[8], s_freem[8];   // wave-uniform -> SGPRs
  #pragma unroll
  for (int k = 0; k < 8; ++k) { s_alive[k] = ~0ull; s_freem[k] = ~0ull; }
  unsigned am[8];                      // per-lane dead mask: 0 or 0xFFFFFFFF
  #pragma unroll
  for (int k = 0; k < 8; ++k) am[k] = 0u;

  unsigned cur[8];
  #pragma unroll
  for (int k = 0; k < 8; ++k) cur[k] = ct[lane + (k << 6)];

  for (int r = 0; r < 32; ++r) {
    unsigned ky[8];
    #pragma unroll
    for (int k = 0; k < 8; ++k) ky[k] = cur[k] | am[k];    // dead -> 0xFFFFFFFF

    // prefetch next row early (ds latency hides under reduce+locate)
    unsigned xn[8];
    if (r < 31) {
      #pragma unroll
      for (int k = 0; k < 8; ++k) xn[k] = ct[((r + 1) << 9) + lane + (k << 6)];
    }

    unsigned mm = umin_(umin_(umin_(ky[0], ky[1]), umin_(ky[2], ky[3])),
                        umin_(umin_(ky[4], ky[5]), umin_(ky[6], ky[7])));
    mm = umin_(mm, (unsigned)dpp_i<0xB1>((int)mm));
    mm = umin_(mm, (unsigned)dpp_i<0x4E>((int)mm));
    mm = umin_(mm, (unsigned)dpp_i<0x141>((int)mm));
    mm = umin_(mm, (unsigned)dpp_i<0x140>((int)mm));
    mm = umin_(mm, (unsigned)dpp_i<0x142>((int)mm));
    mm = umin_(mm, (unsigned)dpp_i<0x143>((int)mm));
    const unsigned s_m = (unsigned)__builtin_amdgcn_readlane((int)mm, 63);

    // ---- branchless exact locate: j1 = min j with ky==s_m ----
    // j = (k<<6)+lane, so min j = min over k of (k<<6)+ctz(hit_k).
    int j1 = 0x7FFFFFFF;
    #pragma unroll
    for (int k = 0; k < 8; ++k) {
      unsigned long long h = __ballot(ky[k] == s_m);
      int cand = h ? ((k << 6) + (int)__builtin_ctzll(h)) : 0x7FFFFFFF;
      j1 = imin_(j1, cand);
    }

    // ---- scalar free test ----
    const int kq = j1 >> 6, ow = j1 & 63;
    unsigned long long fsel = s_freem[0];
    #pragma unroll
    for (int k = 1; k < 8; ++k) fsel = (kq == k) ? s_freem[k] : fsel;
    const bool j1free = (fsel >> ow) & 1ull;

    int jwin;
    if (j1free) {                      // common: assign j1, stays alive
      jwin = j1;
    } else {                           // rare (~1/batch): kill j1, walk to jF
      unsigned lm = (lane == ow) ? 0xFFFFFFFFu : 0u;
      #pragma unroll
      for (int k = 0; k < 8; ++k) {
        am[k]      = (k == kq) ? (am[k] | lm) : am[k];
        s_alive[k] = (k == kq) ? (s_alive[k] & ~(1ull << ow)) : s_alive[k];
      }
      int jF = 0x7FFFFFFF;             // first alive & free column (scalar)
      #pragma unroll
      for (int k = 0; k < 8; ++k) {
        unsigned long long c = s_alive[k] & s_freem[k];
        int cand = c ? ((k << 6) + (int)__builtin_ctzll(c)) : 0x7FFFFFFF;
        jF = imin_(jF, cand);
      }
      const int kF = jF >> 6, lF = jF & 63;
      const unsigned long long lowmask = lF ? ((1ull << lF) - 1ull) : 0ull;
      unsigned lml = (lane < lF) ? 0xFFFFFFFFu : 0u;
      #pragma unroll
      for (int k = 0; k < 8; ++k) {    // kill all alive j < jF (all assigned)
        s_alive[k] = (k < kF) ? 0ull
                   : ((k == kF) ? (s_alive[k] & ~lowmask) : s_alive[k]);
        am[k]      = (k < kF) ? 0xFFFFFFFFu
                   : ((k == kF) ? (am[k] | lml) : am[k]);
      }
      jwin = jF;                       // jF stays alive
    }

    {                                  // assign jwin: clear its free bit
      const int kw = jwin >> 6;
      const unsigned long long wb = ~(1ull << (jwin & 63));
      #pragma unroll
      for (int k = 0; k < 8; ++k)
        s_freem[k] = (k == kw) ? (s_freem[k] & wb) : s_freem[k];
    }
    if (lane == 0) rows_s[r] = jwin;

    if (r < 31) {
      #pragma unroll
      for (int k = 0; k < 8; ++k) cur[k] = xn[k];
    }
  }

  // single-wave epilogue: rank sort (values distinct); same-wave LDS order
  // guarantees visibility of rows_s without a barrier.
  if (lane < 32) {
    int rv = rows_s[lane];
    int rank = 0;
    #pragma unroll
    for (int g = 0; g < 32; ++g) rank += (rows_s[g] < rv) ? 1 : 0;
    out[131072 +       b * 32 + rank] = (float)rv;
    out[131072 + 256 + b * 32 + rank] = (float)lane;
  }
}

// ---------------------------------------------------------------------------

extern "C" void kernel_launch(void* const* d_in, const int* in_sizes, int n_in,
                              void* d_out, int out_size, void* d_ws, size_t ws_size,
                              hipStream_t stream) {
  const float* rel = (const float*)d_in[0];
  const float* hs  = (const float*)d_in[1];
  const float* he  = (const float*)d_in[2];
  const float* ts  = (const float*)d_in[3];
  const float* te  = (const float*)d_in[4];
  const int* grel = (const int*)d_in[5];
  const int* ghs  = (const int*)d_in[6];
  const int* ghe  = (const int*)d_in[7];
  const int* gts  = (const int*)d_in[8];
  const int* gte  = (const int*)d_in[9];

  float* out = (float*)d_out;

  if (ws_size >= 131072 * sizeof(unsigned)) {
    unsigned* T = (unsigned*)d_ws;     // [8][32][512] sortable-transformed cost
    cost_kernel_fused<<<2048, 256, 0, stream>>>(rel, hs, he, ts, te,
                                                grel, ghs, ghe, gts, gte,
                                                out, T);
    hungarian_kernel<true><<<8, 256, 0, stream>>>(T, out);
  } else {
    cost_kernel_single<<<1024, 256, 0, stream>>>(rel, hs, he, ts, te,
                                                 grel, ghs, ghe, gts, gte, out);
    hungarian_kernel<false><<<8, 256, 0, stream>>>(out, out);
  }
}

// Round 10
// 31.752 us; speedup vs baseline: 1.1528x; 1.1528x over previous
//
#include <hip/hip_runtime.h>
#include <hip/hip_bf16.h>
#include <math.h>

// ---------------------------------------------------------------------------
// DPP helpers (controls validated bit-exact rounds 5-8): 0xB1 quad_perm=xor1,
// 0x4E quad_perm=xor2, 0x141 row_half_mirror=xor7, 0x140 row_mirror=xor15,
// 0x142 row_bcast15, 0x143 row_bcast31. Reduce shape: 6 steps -> lane63 ->
// readlane. bound_ctrl zero-fill only pollutes lanes outside lane63's
// dependency cone — safe for min-reduces in u32 and f32.
// ---------------------------------------------------------------------------
template <int CTRL>
__device__ __forceinline__ int dpp_i(int x) {
  return __builtin_amdgcn_update_dpp(0, x, CTRL, 0xF, 0xF, true);
}
template <int CTRL>
__device__ __forceinline__ float dpp_f(float x) {
  return __int_as_float(__builtin_amdgcn_update_dpp(0, __float_as_int(x), CTRL, 0xF, 0xF, true));
}
__device__ __forceinline__ unsigned umin_(unsigned a, unsigned b) { return a < b ? a : b; }
__device__ __forceinline__ int imin_(int a, int b) { return a < b ? a : b; }

// ---------------------------------------------------------------------------
// Per-tensor normalized-softmax gather: c = e_g / sqrt(sum e^2). (S cancels
// exactly — validated rounds 6-8, absmax 0.0.) Reduction trees unchanged.
// ---------------------------------------------------------------------------
template <int NK>
__device__ __forceinline__ float tensor_c(const float* __restrict__ row,
                                          int idx, int lane) {
  float x[4][4];
  float xg = row[idx];
  if (NK == 4) {
    #pragma unroll
    for (int k = 0; k < 4; ++k) {
      float4 v4 = *reinterpret_cast<const float4*>(row + (k << 8) + lane * 4);
      x[k][0] = v4.x; x[k][1] = v4.y; x[k][2] = v4.z; x[k][3] = v4.w;
    }
  } else {
    #pragma unroll
    for (int k = 0; k < 4; ++k) {
      float2 v2 = *reinterpret_cast<const float2*>(row + (k << 7) + lane * 2);
      x[k][0] = v2.x; x[k][1] = v2.y; x[k][2] = 0.0f; x[k][3] = 0.0f;
    }
  }

  float m = -INFINITY;
  #pragma unroll
  for (int k = 0; k < 4; ++k) {
    #pragma unroll
    for (int e = 0; e < 4; ++e) if (e < NK) {
      if (isnan(x[k][e])) x[k][e] = -1e9f;
      m = fmaxf(m, x[k][e]);
    }
  }
  m = fmaxf(m, dpp_f<0xB1>(m));
  m = fmaxf(m, dpp_f<0x4E>(m));
  m = fmaxf(m, dpp_f<0x141>(m));
  m = fmaxf(m, dpp_f<0x140>(m));
  m = fmaxf(m, dpp_f<0x142>(m));
  m = fmaxf(m, dpp_f<0x143>(m));
  float mx = __int_as_float(__builtin_amdgcn_readlane(__float_as_int(m), 63));

  float q[4];
  #pragma unroll
  for (int k = 0; k < 4; ++k) {
    float ls = 0.0f;
    #pragma unroll
    for (int e = 0; e < 4; ++e) if (e < NK) {
      float ev = expf(x[k][e] - mx);
      ls = fmaf(ev, ev, ls);
    }
    q[k] = ls;
  }
  #pragma unroll
  for (int k = 0; k < 4; ++k) {
    q[k] += __shfl_xor(q[k], 32);
    q[k] += __shfl_xor(q[k], 16);
    q[k] += __shfl_xor(q[k], 8);
    q[k] += __shfl_xor(q[k], 4);
    q[k] += dpp_f<0x4E>(q[k]);
    q[k] += dpp_f<0xB1>(q[k]);
  }
  float Q = (q[0] + q[1]) + (q[2] + q[3]);

  if (isnan(xg)) xg = -1e9f;
  float pg = expf(xg - mx);
  return pg / sqrtf(Q);
}

// ---------------------------------------------------------------------------
// Kernel 1 (fused, validated r7-r8): cost to out; sortable ~bits(cost)
// transposed into T[b][g][q] (all costs strictly negative finite -> ~bits is
// an exact order isomorphism; 0xFFFFFFFF unreachable = EXCLUDED).
// ---------------------------------------------------------------------------
__global__ __launch_bounds__(256, 8) void cost_kernel_fused(
    const float* __restrict__ rel,
    const float* __restrict__ hs, const float* __restrict__ he,
    const float* __restrict__ ts, const float* __restrict__ te,
    const int* __restrict__ grel,
    const int* __restrict__ ghs, const int* __restrict__ ghe,
    const int* __restrict__ gts, const int* __restrict__ gte,
    float* __restrict__ cost, unsigned* __restrict__ T)
{
  __shared__ float smB[2][32];
  const int wid   = threadIdx.x >> 6;
  const int lane  = threadIdx.x & 63;
  const int pair  = wid >> 1;
  const int group = wid & 1;
  const int bq    = (blockIdx.x << 1) | pair;
  const int b     = bq >> 9;
  const int gl    = (b << 5) + (lane & 31);

  float accA = 0.0f;
  if (group == 0) {
    accA =        tensor_c<2>(rel + (size_t)bq * 512,  grel[gl], lane);
    accA = fmaf(0.5f, tensor_c<4>(hs + (size_t)bq * 1024, ghs[gl], lane), accA);
    accA = fmaf(0.5f, tensor_c<4>(he + (size_t)bq * 1024, ghe[gl], lane), accA);
  } else {
    float accB = 0.5f * tensor_c<4>(ts + (size_t)bq * 1024, gts[gl], lane);
    accB = fmaf(0.5f, tensor_c<4>(te + (size_t)bq * 1024, gte[gl], lane), accB);
    if (lane < 32) smB[pair][lane] = accB;
  }
  __syncthreads();
  if (group == 0 && lane < 32) {
    float tot = -(accA + smB[pair][lane]);       // same expr as rounds 6-8
    cost[(size_t)bq * 32 + lane] = tot;
    T[(size_t)b * 16384 + lane * 512 + (bq & 511)] = ~__float_as_uint(tot);
  }
}

// Fallback (ws too small): validated single-wave cost straight to out.
__global__ __launch_bounds__(256, 4) void cost_kernel_single(
    const float* __restrict__ rel,
    const float* __restrict__ hs, const float* __restrict__ he,
    const float* __restrict__ ts, const float* __restrict__ te,
    const int* __restrict__ grel,
    const int* __restrict__ ghs, const int* __restrict__ ghe,
    const int* __restrict__ gts, const int* __restrict__ gte,
    float* __restrict__ cost)
{
  const int wid  = threadIdx.x >> 6;
  const int lane = threadIdx.x & 63;
  const int bq   = (blockIdx.x << 2) | wid;
  const int b    = bq >> 9;
  const int gl   = (b << 5) + (lane & 31);
  float acc;
  acc =        tensor_c<2>(rel + (size_t)bq * 512,  grel[gl], lane);
  acc = fmaf(0.5f, tensor_c<4>(hs + (size_t)bq * 1024, ghs[gl], lane), acc);
  acc = fmaf(0.5f, tensor_c<4>(he + (size_t)bq * 1024, ghe[gl], lane), acc);
  acc = fmaf(0.5f, tensor_c<4>(ts + (size_t)bq * 1024, gts[gl], lane), acc);
  acc = fmaf(0.5f, tensor_c<4>(te + (size_t)bq * 1024, gte[gl], lane), acc);
  if (lane < 32) cost[(size_t)bq * 32 + lane] = -acc;
}

// ---------------------------------------------------------------------------
// Value-only u32 min reduce + exact first-j locate (mechanics validated r8).
// ky[k] holds column j = (k<<6)+lane. Returns uniform j1.
// ---------------------------------------------------------------------------
__device__ __forceinline__ int reduce_locate(const unsigned (&ky)[8]) {
  unsigned mm = umin_(umin_(umin_(ky[0], ky[1]), umin_(ky[2], ky[3])),
                      umin_(umin_(ky[4], ky[5]), umin_(ky[6], ky[7])));
  mm = umin_(mm, (unsigned)dpp_i<0xB1>((int)mm));
  mm = umin_(mm, (unsigned)dpp_i<0x4E>((int)mm));
  mm = umin_(mm, (unsigned)dpp_i<0x141>((int)mm));
  mm = umin_(mm, (unsigned)dpp_i<0x140>((int)mm));
  mm = umin_(mm, (unsigned)dpp_i<0x142>((int)mm));
  mm = umin_(mm, (unsigned)dpp_i<0x143>((int)mm));
  const unsigned s_m = (unsigned)__builtin_amdgcn_readlane((int)mm, 63);
  int j1 = 0x7FFFFFFF;
  #pragma unroll
  for (int k = 0; k < 8; ++k) {
    unsigned long long h = __ballot(ky[k] == s_m);
    int cand = h ? ((k << 6) + (int)__builtin_ctzll(h)) : 0x7FFFFFFF;
    j1 = imin_(j1, cand);
  }
  return j1;
}

// ---------------------------------------------------------------------------
// Kernel 2 (round 10 = fixed round 9): collapsed reference-JV replica with
// O(1)-per-turn scalar loop. j1 = argmin over ALIVE columns; alive==all until
// a kill event (E[#kills] ~ 1/batch), so the precomputed per-row GLOBAL
// argmin (4 waves x 8-row ILP) answers almost every turn. Turn loop runs in
// scalar registers (alive/free cselect chains); full-row rescan from global
// only when j1g[r] was killed. Kill-walk semantics validated r3-r8.
// Round-9 compile fix: vrows writelane -> uniform-jwin cndmask select.
// ---------------------------------------------------------------------------
__global__ __launch_bounds__(256) void hungarian_fast(
    const unsigned* __restrict__ T, float* __restrict__ out)
{
  __shared__ int rmj_lds[32];
  __shared__ int rows_lds[32];

  const int b    = blockIdx.x;
  const int w    = threadIdx.x >> 6;
  const int lane = threadIdx.x & 63;
  const unsigned* Tb = T + (size_t)b * 16384;

  // ---- parallel per-row argmin: wave w reduces rows 8w..8w+7 (ILP) ----
  unsigned vals[8][8];
  #pragma unroll
  for (int i = 0; i < 8; ++i) {
    const int row = (w << 3) + i;
    #pragma unroll
    for (int k = 0; k < 8; ++k)
      vals[i][k] = Tb[(row << 9) + (k << 6) + lane];
  }
  #pragma unroll
  for (int i = 0; i < 8; ++i) {
    const int row = (w << 3) + i;
    int j1g = reduce_locate(vals[i]);
    if (lane == 0) rmj_lds[row] = j1g;
  }
  __syncthreads();
  if (threadIdx.x >= 64) return;       // turn loop is single-wave, all-scalar

  const int vrm = rmj_lds[lane & 31];  // lane r holds row r's global argmin

  unsigned long long s_alive[8], s_freem[8];   // wave-uniform -> SGPRs
  #pragma unroll
  for (int k = 0; k < 8; ++k) { s_alive[k] = ~0ull; s_freem[k] = ~0ull; }
  int vrows = 0;                       // lane r accumulates turn r's winner

  for (int r = 0; r < 32; ++r) {
    int j1 = __builtin_amdgcn_readlane(vrm, r);
    int kq = j1 >> 6;

    // alive test (scalar cselect chain)
    unsigned long long asel = s_alive[0];
    #pragma unroll
    for (int k = 1; k < 8; ++k) asel = (kq == k) ? s_alive[k] : asel;
    if (!((asel >> (j1 & 63)) & 1ull)) {
      // rare: j1g killed — rescan row r over alive columns from global
      unsigned ky[8];
      #pragma unroll
      for (int k = 0; k < 8; ++k) {
        unsigned v  = Tb[(r << 9) + (k << 6) + lane];
        unsigned ab = (unsigned)((s_alive[k] >> lane) & 1ull);
        ky[k] = ab ? v : 0xFFFFFFFFu;
      }
      j1 = reduce_locate(ky);
      kq = j1 >> 6;
    }

    // free test (scalar cselect chain)
    unsigned long long fsel = s_freem[0];
    #pragma unroll
    for (int k = 1; k < 8; ++k) fsel = (kq == k) ? s_freem[k] : fsel;
    const bool j1free = (fsel >> (j1 & 63)) & 1ull;

    int jwin;
    if (j1free) {                      // common: assign j1, stays alive
      jwin = j1;
    } else {                           // rare: kill j1, walk to jF (scalar)
      const int ow = j1 & 63;
      #pragma unroll
      for (int k = 0; k < 8; ++k)
        s_alive[k] = (k == kq) ? (s_alive[k] & ~(1ull << ow)) : s_alive[k];
      int jF = 0x7FFFFFFF;             // first alive & free column
      #pragma unroll
      for (int k = 0; k < 8; ++k) {
        unsigned long long c = s_alive[k] & s_freem[k];
        int cand = c ? ((k << 6) + (int)__builtin_ctzll(c)) : 0x7FFFFFFF;
        jF = imin_(jF, cand);
      }
      const int kF = jF >> 6, lF = jF & 63;
      const unsigned long long lowmask = lF ? ((1ull << lF) - 1ull) : 0ull;
      #pragma unroll
      for (int k = 0; k < 8; ++k)      // kill all alive j < jF (all assigned)
        s_alive[k] = (k < kF) ? 0ull
                   : ((k == kF) ? (s_alive[k] & ~lowmask) : s_alive[k]);
      jwin = jF;                       // jF stays alive
    }

    {                                  // assign jwin: clear its free bit
      const int kw = jwin >> 6;
      const unsigned long long wb = ~(1ull << (jwin & 63));
      #pragma unroll
      for (int k = 0; k < 8; ++k)
        s_freem[k] = (k == kw) ? (s_freem[k] & wb) : s_freem[k];
    }
    vrows = (lane == r) ? jwin : vrows;  // jwin uniform: v_cmp + v_cndmask
  }

  // single-wave epilogue: rank sort (values distinct)
  if (lane < 32) rows_lds[lane] = vrows;
  if (lane < 32) {
    int rank = 0;
    #pragma unroll
    for (int g = 0; g < 32; ++g) rank += (rows_lds[g] < vrows) ? 1 : 0;
    out[131072 +       b * 32 + rank] = (float)vrows;
    out[131072 + 256 + b * 32 + rank] = (float)lane;
  }
}

// ---------------------------------------------------------------------------
// Fallback hungarian (ws too small): round-8 LDS-staged version, validated.
// ---------------------------------------------------------------------------
__global__ __launch_bounds__(256) void hungarian_fallback(
    const float* __restrict__ src, float* __restrict__ out)
{
  __shared__ unsigned ct[32 * 512];
  __shared__ int rows_s[32];

  const int b   = blockIdx.x;
  const int tid = threadIdx.x;

  const float4* C4 = reinterpret_cast<const float4*>(src + (size_t)b * 16384);
  #pragma unroll 2
  for (int base = tid; base < 4096; base += 256) {
    float4 v = C4[base];
    int e0 = base << 2, j = e0 >> 5, g = e0 & 31;
    ct[(g + 0) * 512 + j] = ~__float_as_uint(v.x);
    ct[(g + 1) * 512 + j] = ~__float_as_uint(v.y);
    ct[(g + 2) * 512 + j] = ~__float_as_uint(v.z);
    ct[(g + 3) * 512 + j] = ~__float_as_uint(v.w);
  }
  __syncthreads();
  if (tid >= 64) return;
  const int lane = tid;

  unsigned long long s_alive[8], s_freem[8];
  #pragma unroll
  for (int k = 0; k < 8; ++k) { s_alive[k] = ~0ull; s_freem[k] = ~0ull; }
  unsigned am[8];
  #pragma unroll
  for (int k = 0; k < 8; ++k) am[k] = 0u;

  unsigned cur[8];
  #pragma unroll
  for (int k = 0; k < 8; ++k) cur[k] = ct[lane + (k << 6)];

  for (int r = 0; r < 32; ++r) {
    unsigned ky[8];
    #pragma unroll
    for (int k = 0; k < 8; ++k) ky[k] = cur[k] | am[k];
    unsigned xn[8];
    if (r < 31) {
      #pragma unroll
      for (int k = 0; k < 8; ++k) xn[k] = ct[((r + 1) << 9) + lane + (k << 6)];
    }
    int j1 = reduce_locate(ky);
    const int kq = j1 >> 6, ow = j1 & 63;
    unsigned long long fsel = s_freem[0];
    #pragma unroll
    for (int k = 1; k < 8; ++k) fsel = (kq == k) ? s_freem[k] : fsel;
    const bool j1free = (fsel >> ow) & 1ull;

    int jwin;
    if (j1free) {
      jwin = j1;
    } else {
      unsigned lm = (lane == ow) ? 0xFFFFFFFFu : 0u;
      #pragma unroll
      for (int k = 0; k < 8; ++k) {
        am[k]      = (k == kq) ? (am[k] | lm) : am[k];
        s_alive[k] = (k == kq) ? (s_alive[k] & ~(1ull << ow)) : s_alive[k];
      }
      int jF = 0x7FFFFFFF;
      #pragma unroll
      for (int k = 0; k < 8; ++k) {
        unsigned long long c = s_alive[k] & s_freem[k];
        int cand = c ? ((k << 6) + (int)__builtin_ctzll(c)) : 0x7FFFFFFF;
        jF = imin_(jF, cand);
      }
      const int kF = jF >> 6, lF = jF & 63;
      const unsigned long long lowmask = lF ? ((1ull << lF) - 1ull) : 0ull;
      unsigned lml = (lane < lF) ? 0xFFFFFFFFu : 0u;
      #pragma unroll
      for (int k = 0; k < 8; ++k) {
        s_alive[k] = (k < kF) ? 0ull
                   : ((k == kF) ? (s_alive[k] & ~lowmask) : s_alive[k]);
        am[k]      = (k < kF) ? 0xFFFFFFFFu
                   : ((k == kF) ? (am[k] | lml) : am[k]);
      }
      jwin = jF;
    }
    const int kw = jwin >> 6;
    const unsigned long long wb = ~(1ull << (jwin & 63));
    #pragma unroll
    for (int k = 0; k < 8; ++k)
      s_freem[k] = (k == kw) ? (s_freem[k] & wb) : s_freem[k];
    if (lane == 0) rows_s[r] = jwin;
    if (r < 31) {
      #pragma unroll
      for (int k = 0; k < 8; ++k) cur[k] = xn[k];
    }
  }

  if (lane < 32) {
    int rv = rows_s[lane];
    int rank = 0;
    #pragma unroll
    for (int g = 0; g < 32; ++g) rank += (rows_s[g] < rv) ? 1 : 0;
    out[131072 +       b * 32 + rank] = (float)rv;
    out[131072 + 256 + b * 32 + rank] = (float)lane;
  }
}

// ---------------------------------------------------------------------------

extern "C" void kernel_launch(void* const* d_in, const int* in_sizes, int n_in,
                              void* d_out, int out_size, void* d_ws, size_t ws_size,
                              hipStream_t stream) {
  const float* rel = (const float*)d_in[0];
  const float* hs  = (const float*)d_in[1];
  const float* he  = (const float*)d_in[2];
  const float* ts  = (const float*)d_in[3];
  const float* te  = (const float*)d_in[4];
  const int* grel = (const int*)d_in[5];
  const int* ghs  = (const int*)d_in[6];
  const int* ghe  = (const int*)d_in[7];
  const int* gts  = (const int*)d_in[8];
  const int* gte  = (const int*)d_in[9];

  float* out = (float*)d_out;

  if (ws_size >= 131072 * sizeof(unsigned)) {
    unsigned* T = (unsigned*)d_ws;     // [8][32][512] sortable-transformed cost
    cost_kernel_fused<<<2048, 256, 0, stream>>>(rel, hs, he, ts, te,
                                                grel, ghs, ghe, gts, gte,
                                                out, T);
    hungarian_fast<<<8, 256, 0, stream>>>(T, out);
  } else {
    cost_kernel_single<<<1024, 256, 0, stream>>>(rel, hs, he, ts, te,
                                                 grel, ghs, ghe, gts, gte, out);
    hungarian_fallback<<<8, 256, 0, stream>>>(out, out);
  }
}